// Round 2
// baseline (129.770 us; speedup 1.0000x reference)
//
#include <hip/hip_runtime.h>

typedef unsigned short u16;
typedef unsigned int u32;
typedef __attribute__((ext_vector_type(8))) short short8;   // 8 x bf16 (4 VGPRs)
typedef __attribute__((ext_vector_type(4))) float floatx4;  // MFMA acc

#define LSTRIDE 72   // u16 elements per LDS row: 64 + 8 pad -> 16B groups spread over all 8

__device__ __forceinline__ u16 f2bf_rne(float f) {
  u32 u = __float_as_uint(f);
  u += 0x7fffu + ((u >> 16) & 1u);      // round-to-nearest-even
  return (u16)(u >> 16);
}
__device__ __forceinline__ short i2bf_exact(int v) {  // v in [0,256): exact in bf16
  return (short)(__float_as_uint((float)v) >> 16);
}

// ---------------------------------------------------------------------------
// prep: build Bt[(p,o)][m] = (2/255)*Wpad[m-p][o] as bf16 (1024 x 512, row-major)
// plus colsum[o] = sum_c W[c][o]. Bt is shared by all 2048 sub-blocks.
// blocks 0..255: Bt ; block 256: colsum.
// ---------------------------------------------------------------------------
__global__ __launch_bounds__(256) void prep_kernel(const float* __restrict__ Wm,
                                                   u16* __restrict__ Btg,
                                                   float* __restrict__ csum_g) {
  const int b = blockIdx.x;
  const int t = threadIdx.x;
  if (b < 256) {
    int gid = b * 256 + t;
    int o = gid & 63;          // lane-contiguous -> coalesced W reads
    int rest = gid >> 6;
    int m8 = rest & 63;        // m-group of 8
    int p = rest >> 6;         // 0..15
    const float scale = 2.0f / 255.0f;
    short8 v;
    #pragma unroll
    for (int j = 0; j < 8; ++j) {
      int c = m8 * 8 + j - p;
      float f = (c >= 0 && c < 496) ? Wm[c * 64 + o] * scale : 0.0f;
      v[j] = (short)f2bf_rne(f);
    }
    *(short8*)&Btg[((long)(p * 64 + o)) * 512 + m8 * 8] = v;   // 16B aligned
  } else {
    __shared__ float red[256];
    int o = t & 63, seg = t >> 6;
    float s = 0.0f;
    for (int c = seg; c < 496; c += 4) s += Wm[c * 64 + o];
    red[t] = s;
    __syncthreads();
    if (t < 64) csum_g[t] = red[t] + red[t + 64] + red[t + 128] + red[t + 192];
  }
}

// ---------------------------------------------------------------------------
// GEMM: C[mr][n] = sum_m A[mr][m] * Bt[n][m]
//   A[mr = bid*8+q][m] = w[q][m] of sub-block bid (ints 0..255, exact bf16),
//   computed in-staging from x (3 vector loads + shifts per 8x8 tile).
// BM=128 (16 sub-blocks), BN=128, BK=64. 4 waves in 2x2, each 64x64.
// out[bid][p*8+q][o] = C[mr][(p,o)] - colsum[o].
// ---------------------------------------------------------------------------
__global__ __launch_bounds__(256, 4) void gemm_kernel(
    const int* __restrict__ x, const u16* __restrict__ Btg,
    const float* __restrict__ csum_g, float* __restrict__ out) {
  __shared__ __align__(16) u16 As[128 * LSTRIDE];
  __shared__ __align__(16) u16 Bs[128 * LSTRIDE];

  const int t = threadIdx.x;
  const int mtile = blockIdx.x;        // 0..127
  const int n0 = blockIdx.y * 128;     // 0..7 n-tiles

  const int wave = t >> 6, lane = t & 63;
  const int wm = wave >> 1, wn = wave & 1;      // 2x2 wave grid
  const int quad = lane >> 4, l16 = lane & 15;

  // A-staging decomposition: thread -> (sub, k-group, q-half)
  const int sA_sub = t >> 4;           // 0..15
  const int sA_kg  = (t >> 1) & 7;     // 0..7
  const int sA_qh  = t & 1;            // 0..1
  const long xrow = ((long)mtile * 16 + sA_sub) * 512;

  floatx4 acc[4][4];
  #pragma unroll
  for (int mt = 0; mt < 4; ++mt)
    #pragma unroll
    for (int nt = 0; nt < 4; ++nt)
      acc[mt][nt] = floatx4{0.f, 0.f, 0.f, 0.f};

  for (int kc = 0; kc < 8; ++kc) {
    const int k0 = kc * 64;
    __syncthreads();                   // drain previous chunk's LDS reads
    // ---- stage A: bytes -> 8-bit windows -> bf16 (exact), ds_write_b128
    {
      const int base = k0 + sA_kg * 8;
      int4 a0 = *(const int4*)&x[xrow + base];
      int4 a1 = *(const int4*)&x[xrow + base + 4];
      int c8 = (base + 8 < 512) ? x[xrow + base + 8] : 0;  // per-sub-block zero pad
      int c[9] = {a0.x, a0.y, a0.z, a0.w, a1.x, a1.y, a1.z, a1.w, c8};
      #pragma unroll
      for (int qi = 0; qi < 4; ++qi) {
        const int q = sA_qh * 4 + qi;
        short8 w;
        #pragma unroll
        for (int j = 0; j < 8; ++j) {
          int v = ((c[j] << q) & 255) + ((c[j + 1] & 255) >> (8 - q));
          w[j] = i2bf_exact(v);
        }
        *(short8*)&As[(sA_sub * 8 + q) * LSTRIDE + sA_kg * 8] = w;
      }
    }
    // ---- stage B: plain aligned copies from Bt
    #pragma unroll
    for (int pass = 0; pass < 4; ++pass) {
      int flat = t + pass * 256;       // 0..1023
      int n = flat >> 3, kgl = flat & 7;
      short8 bv = *(const short8*)&Btg[(long)(n0 + n) * 512 + k0 + kgl * 8];
      *(short8*)&Bs[n * LSTRIDE + kgl * 8] = bv;
    }
    __syncthreads();
    // ---- compute: 2 k-steps of 32, all fragments aligned ds_read_b128
    #pragma unroll
    for (int ks = 0; ks < 2; ++ks) {
      const int koff = ks * 32 + quad * 8;
      short8 af[4], bf[4];
      #pragma unroll
      for (int mt = 0; mt < 4; ++mt)
        af[mt] = *(const short8*)&As[(wm * 64 + mt * 16 + l16) * LSTRIDE + koff];
      #pragma unroll
      for (int nt = 0; nt < 4; ++nt)
        bf[nt] = *(const short8*)&Bs[(wn * 64 + nt * 16 + l16) * LSTRIDE + koff];
      #pragma unroll
      for (int mt = 0; mt < 4; ++mt)
        #pragma unroll
        for (int nt = 0; nt < 4; ++nt)
          acc[mt][nt] = __builtin_amdgcn_mfma_f32_16x16x32_bf16(
              af[mt], bf[nt], acc[mt][nt], 0, 0, 0);
    }
  }

  // ---- epilogue: C/D layout col=l16, row=quad*4+reg ; scatter to (bid, p*8+q, o)
  #pragma unroll
  for (int nt = 0; nt < 4; ++nt) {
    int n = n0 + wn * 64 + nt * 16 + l16;
    int p = n >> 6, o = n & 63;
    float cs = csum_g[o];
    #pragma unroll
    for (int mt = 0; mt < 4; ++mt) {
      int mbase = mtile * 128 + wm * 64 + mt * 16 + quad * 4;
      #pragma unroll
      for (int i = 0; i < 4; ++i) {
        int mr = mbase + i;
        int bid = mr >> 3, q = mr & 7;
        out[(long)bid * 8192 + (p * 8 + q) * 64 + o] = acc[mt][nt][i] - cs;
      }
    }
  }
}

extern "C" void kernel_launch(void* const* d_in, const int* in_sizes, int n_in,
                              void* d_out, int out_size, void* d_ws, size_t ws_size,
                              hipStream_t stream) {
  const int* x = (const int*)d_in[0];        // (256, 4096) byte values as int32
  const float* Wm = (const float*)d_in[1];   // (496, 64) fp32
  float* out = (float*)d_out;                // (256, 8, 128, 64) fp32

  u16* Btg = (u16*)d_ws;                             // 1024*512*2 = 1 MB
  float* csum_g = (float*)((char*)d_ws + (1u << 20)); // 256 B

  prep_kernel<<<dim3(257), dim3(256), 0, stream>>>(Wm, Btg, csum_g);
  gemm_kernel<<<dim3(128, 8), dim3(256), 0, stream>>>(x, Btg, csum_g, out);
}

// Round 3
// 102.976 us; speedup vs baseline: 1.2602x; 1.2602x over previous
//
#include <hip/hip_runtime.h>

typedef unsigned short u16;
typedef unsigned int u32;
typedef __attribute__((ext_vector_type(8))) short short8;     // 8 x 16-bit
typedef _Float16 half8 __attribute__((ext_vector_type(8)));   // MFMA A/B frag
typedef __attribute__((ext_vector_type(4))) float floatx4;    // MFMA acc

#define LSTRIDE 72   // u16 per LDS row: 64 + 8 pad; rows 16B-aligned, bank-clean

// ---------------------------------------------------------------------------
// Fused: out[bid][p*8+q][o] = S*acc - (1024*S+1)*csumB[o],  S = 2/255
//   acc = sum_m A[(sub,q)][m] * B[(p,o)][m]
//   A[(sub,q)][m] = fp16(1024 + w[q][m])   (exact; w = 8-bit sliding windows)
//   B[(p,o)][m]   = fp16(Wpad[m-p][o])     (Toeplitz shift baked at staging)
// BM=128 (16 subs x 8 q), BN=128 (2 p x 64 o), BK=64. 4 waves 2x2, 64x64 each.
// ---------------------------------------------------------------------------
__global__ __launch_bounds__(256, 4) void byteformer_fused(
    const int* __restrict__ x, const float* __restrict__ Wm,
    float* __restrict__ out) {
  __shared__ __align__(16) u16 As[128 * LSTRIDE];
  __shared__ __align__(16) u16 Bs[128 * LSTRIDE];
  __shared__ float part[256];
  __shared__ float csum[64];

  const int t = threadIdx.x;
  const int mtile = blockIdx.x;        // 0..127 (16 sub-blocks each)
  const int n0 = blockIdx.y * 128;     // 8 n-tiles
  const int p0 = 2 * blockIdx.y;       // base shift for this block's B rows

  const int wave = t >> 6, lane = t & 63;
  const int wm = wave >> 1, wn = wave & 1;
  const int quad = lane >> 4, l16 = lane & 15;

  // A staging: thread -> (sub, k-group, q-half)
  const int sA_sub = t >> 4;           // 0..15
  const int sA_kg  = (t >> 1) & 7;     // 0..7
  const int sA_qh  = t & 1;            // 0..1
  const long xrow = ((long)mtile * 16 + sA_sub) * 512;

  // B staging: wave wv handles m-groups {2wv, 2wv+1}, lane -> o
  const int sB_o = lane;               // 0..63 (wave-coalesced W reads)

  floatx4 acc[4][4];
  #pragma unroll
  for (int mt = 0; mt < 4; ++mt)
    #pragma unroll
    for (int nt = 0; nt < 4; ++nt)
      acc[mt][nt] = floatx4{0.f, 0.f, 0.f, 0.f};

  float csum_local = 0.0f;

  for (int kc = 0; kc < 8; ++kc) {
    const int k0 = kc * 64;
    __syncthreads();                   // previous chunk's LDS reads done

    // ---- stage A: bytes -> windows -> fp16(1024+v) via 0x6400|v (no cvt)
    {
      const int base = k0 + sA_kg * 8;
      int4 a0 = *(const int4*)&x[xrow + base];
      int4 a1 = *(const int4*)&x[xrow + base + 4];
      int c8 = (base + 8 < 512) ? x[xrow + base + 8] : 0;
      int c[9] = {a0.x, a0.y, a0.z, a0.w, a1.x, a1.y, a1.z, a1.w, c8};
      u32 w16[8];
      #pragma unroll
      for (int j = 0; j < 8; ++j) w16[j] = ((u32)c[j] << 8) | (u32)c[j + 1];
      #pragma unroll
      for (int qi = 0; qi < 4; ++qi) {
        const int q = sA_qh * 4 + qi;
        const int sh = 8 - q;
        u32 d[4];
        #pragma unroll
        for (int jp = 0; jp < 4; ++jp) {
          u32 v0 = (w16[2 * jp] >> sh) & 255u;
          u32 v1 = (w16[2 * jp + 1] >> sh) & 255u;
          d[jp] = v0 | (v1 << 16) | 0x64006400u;
        }
        *(u32*)&As[(sA_sub * 8 + q) * LSTRIDE + sA_kg * 8 + 0] = d[0];
        *(u32*)&As[(sA_sub * 8 + q) * LSTRIDE + sA_kg * 8 + 2] = d[1];
        *(u32*)&As[(sA_sub * 8 + q) * LSTRIDE + sA_kg * 8 + 4] = d[2];
        *(u32*)&As[(sA_sub * 8 + q) * LSTRIDE + sA_kg * 8 + 6] = d[3];
      }
    }

    // ---- stage B: 17 coalesced W reads -> fp16 -> 4 shifted b128 rows
    {
      const int cbase = k0 + 16 * wave - p0 - 1;
      float f[17];
      u16 h[17];
      #pragma unroll
      for (int j = 0; j < 17; ++j) {
        int c = cbase + j;                       // wave-uniform
        float v = (c >= 0 && c < 496) ? Wm[c * 64 + sB_o] : 0.0f;
        f[j] = v;
        h[j] = (u16)__builtin_bit_cast(unsigned short, (_Float16)v);
      }
      #pragma unroll
      for (int j = 1; j <= 16; ++j) csum_local += f[j];  // pp=0 coverage: full W
      #pragma unroll
      for (int g = 0; g < 2; ++g) {              // m-groups 2*wave+g
        const int mgrp = 2 * wave + g;
        #pragma unroll
        for (int pp = 0; pp < 2; ++pp) {
          const int jb = g * 8 + 1 - pp;
          u32 d[4];
          #pragma unroll
          for (int di = 0; di < 4; ++di)
            d[di] = (u32)h[jb + 2 * di] | ((u32)h[jb + 2 * di + 1] << 16);
          u32* dst = (u32*)&Bs[(pp * 64 + sB_o) * LSTRIDE + mgrp * 8];
          dst[0] = d[0]; dst[1] = d[1]; dst[2] = d[2]; dst[3] = d[3];
        }
      }
    }
    __syncthreads();

    // ---- compute: 2 k-steps of 32, aligned ds_read_b128 fragments
    #pragma unroll
    for (int ks = 0; ks < 2; ++ks) {
      const int koff = ks * 32 + quad * 8;
      half8 af[4], bf[4];
      #pragma unroll
      for (int mt = 0; mt < 4; ++mt)
        af[mt] = *(const half8*)&As[(wm * 64 + mt * 16 + l16) * LSTRIDE + koff];
      #pragma unroll
      for (int nt = 0; nt < 4; ++nt)
        bf[nt] = *(const half8*)&Bs[(wn * 64 + nt * 16 + l16) * LSTRIDE + koff];
      #pragma unroll
      for (int mt = 0; mt < 4; ++mt)
        #pragma unroll
        for (int nt = 0; nt < 4; ++nt)
          acc[mt][nt] = __builtin_amdgcn_mfma_f32_16x16x32_f16(
              af[mt], bf[nt], acc[mt][nt], 0, 0, 0);
    }
  }

  // ---- csumB reduction: part[wave*64+o] -> csum[o]
  part[t] = csum_local;
  __syncthreads();
  if (t < 64)
    csum[t] = part[t] + part[t + 64] + part[t + 128] + part[t + 192];
  __syncthreads();

  // ---- epilogue: C/D layout col=l16, row=quad*4+reg
  const float S = 2.0f / 255.0f;
  const float K1 = 1024.0f * S + 1.0f;
  #pragma unroll
  for (int nt = 0; nt < 4; ++nt) {
    int n = n0 + wn * 64 + nt * 16 + l16;
    int p = n >> 6, o = n & 63;
    float cs = K1 * csum[o];
    #pragma unroll
    for (int mt = 0; mt < 4; ++mt) {
      int mbase = mtile * 128 + wm * 64 + mt * 16 + quad * 4;
      #pragma unroll
      for (int i = 0; i < 4; ++i) {
        int mr = mbase + i;
        int bid = mr >> 3, q = mr & 7;
        out[(long)bid * 8192 + (p * 8 + q) * 64 + o] = S * acc[mt][nt][i] - cs;
      }
    }
  }
}

extern "C" void kernel_launch(void* const* d_in, const int* in_sizes, int n_in,
                              void* d_out, int out_size, void* d_ws, size_t ws_size,
                              hipStream_t stream) {
  const int* x = (const int*)d_in[0];        // (256, 4096) byte values as int32
  const float* Wm = (const float*)d_in[1];   // (496, 64) fp32
  float* out = (float*)d_out;                // (256, 8, 128, 64) fp32
  byteformer_fused<<<dim3(128, 8), dim3(256), 0, stream>>>(x, Wm, out);
}